// Round 1
// baseline (70.017 us; speedup 1.0000x reference)
//
#include <hip/hip_runtime.h>
#include <stdint.h>

#define NXD 2048
#define NYD 2048
#define DIMD 28
// class nibble table: v -> class, classes = [1,1,1,0,0,0,0,2] packed low->high
#define CLS_TABLE 0x20000111u

// Pack one row of 28 values (each 0..7) into 10 used dwords:
//   bits [0,224): value one-hot at d*8+v        (words 0..6)
//   bits [0,84) of cls mask: class one-hot d*3+c (words 7..9)
// popcount(AND of packs) = eq_cnt + cls_cnt.
__device__ __forceinline__ void pack_row(const int* __restrict__ src,
                                         uint32_t* __restrict__ w /*[12]*/) {
    int vals[DIMD];
    const int4* s4 = (const int4*)src;   // 28 ints = 7x int4, rows 112B -> 16B aligned
#pragma unroll
    for (int q = 0; q < 7; ++q) {
        int4 t = s4[q];
        vals[4*q+0] = t.x; vals[4*q+1] = t.y;
        vals[4*q+2] = t.z; vals[4*q+3] = t.w;
    }
    unsigned long long e0=0, e1=0, e2=0, e3=0, c0=0, c1=0;
#pragma unroll
    for (int d = 0; d < DIMD; ++d) {
        const int v = vals[d];
        // (d*8)&63 and the word index are compile-time after unroll (no crossing)
        const unsigned long long eb = 1ull << (((d*8) & 63) + v);
        if      (d < 8)  e0 |= eb;
        else if (d < 16) e1 |= eb;
        else if (d < 24) e2 |= eb;
        else             e3 |= eb;
        const int c = (CLS_TABLE >> (4*v)) & 0xF;   // 0..2
        if      (d*3 + 2 < 64) c0 |= 1ull << (d*3 + c);
        else if (d*3 >= 64)    c1 |= 1ull << (d*3 - 64 + c);
        else {                                  // d == 21: bits 63..65 straddle
            const unsigned long long b = 1ull << c;
            c0 |= (b & 1ull) << 63;             // c==0 -> bit 63
            c1 |= b >> 1;                       // c==1/2 -> bits 0/1
        }
    }
    w[0]=(uint32_t)e0; w[1]=(uint32_t)(e0>>32);
    w[2]=(uint32_t)e1; w[3]=(uint32_t)(e1>>32);
    w[4]=(uint32_t)e2; w[5]=(uint32_t)(e2>>32);
    w[6]=(uint32_t)e3;                          // bits 192..223
    w[7]=(uint32_t)c0; w[8]=(uint32_t)(c0>>32);
    w[9]=(uint32_t)c1;
    w[10]=0u; w[11]=0u;
}

// Workspace layout (uint4 units):
//   t4: [3][NYD]  quad-major -> quad q of t-row j at ws[q*NYD + j]
//   r4: [3][NXD]  at offset 3*NYD
// Quad-major makes the compute kernel's T loads perfectly coalesced
// (64 lanes x consecutive uint4 = 1 KB per wave load instruction).
__global__ __launch_bounds__(256) void pack_all(
    const int* __restrict__ set_r, const int* __restrict__ set_t,
    uint4* __restrict__ ws)
{
    const int idx = blockIdx.x * 256 + threadIdx.x;   // 0..4095
    const bool is_t = (idx < NYD);                    // wave-uniform (2048 % 64 == 0)
    const int row = is_t ? idx : idx - NYD;
    const int* src = is_t ? (set_t + (size_t)row * DIMD)
                          : (set_r + (size_t)row * DIMD);
    uint32_t w[12];
    pack_row(src, w);
    uint4* base = ws + (is_t ? 0 : 3 * NYD);
    base[0 * NYD + row] = make_uint4(w[0], w[1], w[2], w[3]);
    base[1 * NYD + row] = make_uint4(w[4], w[5], w[6], w[7]);
    base[2 * NYD + row] = make_uint4(w[8], w[9], 0u, 0u);
}

// Pure-register compute kernel. Tile 16 i-rows x 256 j-cols, 256 threads,
// grid (8, 128) = 1024 blocks = 4096 waves = 4 waves/SIMD (2x the fused
// version's occupancy). No LDS, no barrier: T-packs in 48 VGPRs from
// coalesced L2-resident loads; R-packs are wave-uniform (L1 broadcast).
__global__ __launch_bounds__(256, 4) void dist_kernel(
    const uint4* __restrict__ ws, const float* __restrict__ sigma_p,
    float* __restrict__ out)
{
    const int tid  = threadIdx.x;
    const int lane = tid & 63;
    const int wave = tid >> 6;
    const int i0 = blockIdx.y * 16;
    const int j0 = blockIdx.x * 256;

    const uint4* t4 = ws;             // [3][NYD]
    const uint4* r4 = ws + 3 * NYD;   // [3][NXD]

    uint4 T[4][3];
#pragma unroll
    for (int s = 0; s < 4; ++s) {
        const int j = j0 + lane + 64 * s;
#pragma unroll
        for (int q = 0; q < 3; ++q) T[s][q] = t4[q * NYD + j];
    }

    const float sg = sigma_p[0];
    // out = exp(-((56-s)/28)^2 / (2 sigma^2)) = exp(-(56-s)^2 * k)
    const float k = 1.0f / (2.0f * sg * sg * (float)(DIMD * DIMD));

    const int irow = i0 + wave * 4;
    float* obase = out + (size_t)irow * NYD + j0 + lane;

#pragma unroll
    for (int ii = 0; ii < 4; ++ii) {
        const uint4 R0 = r4[0 * NXD + irow + ii];   // wave-uniform
        const uint4 R1 = r4[1 * NXD + irow + ii];
        const uint4 R2 = r4[2 * NXD + irow + ii];
#pragma unroll
        for (int s = 0; s < 4; ++s) {
            const int sum =
                __popc(R0.x & T[s][0].x) + __popc(R0.y & T[s][0].y) +
                __popc(R0.z & T[s][0].z) + __popc(R0.w & T[s][0].w) +
                __popc(R1.x & T[s][1].x) + __popc(R1.y & T[s][1].y) +
                __popc(R1.z & T[s][1].z) + __popc(R1.w & T[s][1].w) +
                __popc(R2.x & T[s][2].x) + __popc(R2.y & T[s][2].y);
            const float c = (float)(56 - sum);
            // 64 lanes -> 256 B contiguous dword store, fully coalesced
            obase[(size_t)ii * NYD + 64 * s] = __expf(-c * c * k);
        }
    }
}

extern "C" void kernel_launch(void* const* d_in, const int* in_sizes, int n_in,
                              void* d_out, int out_size, void* d_ws, size_t ws_size,
                              hipStream_t stream) {
    const int*   set_r = (const int*)d_in[0];
    const int*   set_t = (const int*)d_in[1];
    const float* sigma = (const float*)d_in[2];
    float*       out   = (float*)d_out;
    uint4*       ws    = (uint4*)d_ws;   // needs 2*3*2048*16 B = 192 KiB

    // Phase 1: pack all 4096 rows once (removes the old 64x per-tile
    // re-packing redundancy and the in-kernel barrier/LDS phase).
    pack_all<<<dim3(4096 / 256), dim3(256), 0, stream>>>(set_r, set_t, ws);

    // Phase 2: 16x256 tiles -> grid (8, 128) = 1024 blocks.
    dist_kernel<<<dim3(NYD / 256, NXD / 16), dim3(256), 0, stream>>>(
        ws, sigma, out);
}

// Round 2
// 67.901 us; speedup vs baseline: 1.0312x; 1.0312x over previous
//
#include <hip/hip_runtime.h>
#include <stdint.h>

#define NXD 2048
#define NYD 2048
#define DIMD 28
// class nibble table: v -> class, classes = [1,1,1,0,0,0,0,2] packed low->high
#define CLS_TABLE 0x20000111u

// Pack one row of 28 values (each 0..7) into 10 used dwords:
//   bits [0,224): value one-hot at d*8+v        (words 0..6)
//   bits [0,84) of cls mask: class one-hot d*3+c (words 7..9)
// popcount(AND of packs) = eq_cnt + cls_cnt.
__device__ __forceinline__ void pack_row(const int* __restrict__ src,
                                         uint32_t* __restrict__ w /*[12]*/) {
    int vals[DIMD];
    const int4* s4 = (const int4*)src;   // 28 ints = 7x int4, rows 112B -> 16B aligned
#pragma unroll
    for (int q = 0; q < 7; ++q) {
        int4 t = s4[q];
        vals[4*q+0] = t.x; vals[4*q+1] = t.y;
        vals[4*q+2] = t.z; vals[4*q+3] = t.w;
    }
    unsigned long long e0=0, e1=0, e2=0, e3=0, c0=0, c1=0;
#pragma unroll
    for (int d = 0; d < DIMD; ++d) {
        const int v = vals[d];
        // (d*8)&63 and the word index are compile-time after unroll (no crossing)
        const unsigned long long eb = 1ull << (((d*8) & 63) + v);
        if      (d < 8)  e0 |= eb;
        else if (d < 16) e1 |= eb;
        else if (d < 24) e2 |= eb;
        else             e3 |= eb;
        const int c = (CLS_TABLE >> (4*v)) & 0xF;   // 0..2
        if      (d*3 + 2 < 64) c0 |= 1ull << (d*3 + c);
        else if (d*3 >= 64)    c1 |= 1ull << (d*3 - 64 + c);
        else {                                  // d == 21: bits 63..65 straddle
            const unsigned long long b = 1ull << c;
            c0 |= (b & 1ull) << 63;             // c==0 -> bit 63
            c1 |= b >> 1;                       // c==1/2 -> bits 0/1
        }
    }
    w[0]=(uint32_t)e0; w[1]=(uint32_t)(e0>>32);
    w[2]=(uint32_t)e1; w[3]=(uint32_t)(e1>>32);
    w[4]=(uint32_t)e2; w[5]=(uint32_t)(e2>>32);
    w[6]=(uint32_t)e3;                          // bits 192..223
    w[7]=(uint32_t)c0; w[8]=(uint32_t)(c0>>32);
    w[9]=(uint32_t)c1;
    w[10]=0u; w[11]=0u;
}

// Single fused kernel, ONE launch (round-1's split cost an extra graph node
// for no kernel-side gain). Block = 256 threads, tile 16 i-rows x 256 j-cols
// -> grid (8,128) = 1024 blocks = 4 blocks/CU (2x round -1's occupancy).
// Phase 1: thread tid packs t-row j0+tid (tid<16 also packs r-row i0+tid)
// into LDS. Redundant re-packing across i-blocks costs ~0.3 us total.
// Phase 2: thread holds 4 t-packs (rows lane+64s, stride 12 dwords ->
// bank-balanced b128 reads) in registers; r-packs read wave-uniform
// (LDS broadcast, conflict-free).
__global__ __launch_bounds__(256, 4) void setdist_kernel(
    const int* __restrict__ set_r, const int* __restrict__ set_t,
    const float* __restrict__ sigma_p, float* __restrict__ out)
{
    __shared__ uint32_t t_pk[256][12];   // 12 KB
    __shared__ uint32_t r_pk[16][12];    // 768 B

    const int tid = threadIdx.x;
    const int i0 = blockIdx.y * 16;
    const int j0 = blockIdx.x * 256;

    {
        uint32_t w[12];
        pack_row(set_t + (size_t)(j0 + tid) * DIMD, w);
        uint4* dst = (uint4*)t_pk[tid];
        dst[0] = make_uint4(w[0], w[1], w[2], w[3]);
        dst[1] = make_uint4(w[4], w[5], w[6], w[7]);
        dst[2] = make_uint4(w[8], w[9], 0u, 0u);
    }
    if (tid < 16) {
        uint32_t w[12];
        pack_row(set_r + (size_t)(i0 + tid) * DIMD, w);
        uint4* dst = (uint4*)r_pk[tid];
        dst[0] = make_uint4(w[0], w[1], w[2], w[3]);
        dst[1] = make_uint4(w[4], w[5], w[6], w[7]);
        dst[2] = make_uint4(w[8], w[9], 0u, 0u);
    }

    const float sg = sigma_p[0];
    // out = exp(-((56-s)/28)^2 / (2 sigma^2)) = exp(-(56-s)^2 * k)
    const float k = 1.0f / (2.0f * sg * sg * (float)(DIMD * DIMD));

    __syncthreads();

    const int lane = tid & 63;
    const int wave = tid >> 6;

    // 4 t-packs in registers; rows lane + 64*s -> lane stride 12 dw -> all 32
    // banks hit exactly 8x per b128 wave-read (structural minimum, no penalty)
    uint4 T[4][3];
#pragma unroll
    for (int s = 0; s < 4; ++s) {
        const uint4* tp = (const uint4*)t_pk[lane + 64*s];
        T[s][0] = tp[0]; T[s][1] = tp[1]; T[s][2] = tp[2];
    }

    const int irow = wave * 4;
    float* obase = out + (size_t)(i0 + irow) * NYD + j0 + lane;

#pragma unroll
    for (int ii = 0; ii < 4; ++ii) {
        const uint4* rp = (const uint4*)r_pk[irow + ii];  // wave-uniform
        const uint4 R0 = rp[0], R1 = rp[1], R2 = rp[2];
#pragma unroll
        for (int s = 0; s < 4; ++s) {
            const int sum =
                __popc(R0.x & T[s][0].x) + __popc(R0.y & T[s][0].y) +
                __popc(R0.z & T[s][0].z) + __popc(R0.w & T[s][0].w) +
                __popc(R1.x & T[s][1].x) + __popc(R1.y & T[s][1].y) +
                __popc(R1.z & T[s][1].z) + __popc(R1.w & T[s][1].w) +
                __popc(R2.x & T[s][2].x) + __popc(R2.y & T[s][2].y);
            const float c = (float)(56 - sum);
            // 64 lanes -> 256 B contiguous dword store, fully coalesced
            obase[(size_t)ii * NYD + 64 * s] = __expf(-c * c * k);
        }
    }
}

extern "C" void kernel_launch(void* const* d_in, const int* in_sizes, int n_in,
                              void* d_out, int out_size, void* d_ws, size_t ws_size,
                              hipStream_t stream) {
    const int*   set_r = (const int*)d_in[0];
    const int*   set_t = (const int*)d_in[1];
    const float* sigma = (const float*)d_in[2];
    float*       out   = (float*)d_out;

    // 16x256 tiles -> grid (8, 128) = 1024 blocks, one launch
    setdist_kernel<<<dim3(NYD / 256, NXD / 16), dim3(256), 0, stream>>>(
        set_r, set_t, sigma, out);
}